// Round 1
// baseline (138.643 us; speedup 1.0000x reference)
//
#include <hip/hip_runtime.h>
#include <hip/hip_bf16.h>

// Problem constants (SymmetricTransitionDown): B=4, N=16384, C=64, O=64,
// RADIUS=8, STRIDE=4, S=16, M=N/STRIDE=4096, total rows B*N=65536.
#define NPTS   16384
#define NMASK  16383
#define MPTS   4096
#define NROWS  65536
#define EPSV   1e-5f

// ---------------------------------------------------------------------------
// Kernel A: per-row precompute.
//   g[r][c] = sum_j f[r][j] * w1[2+j][c]
//   y[r][c] = relu(bn2(sum_j f[r][j] * w3[j][c]))
// Row-per-lane: lane l owns row (wid*64+l); 64 fp32 accumulators in VGPRs.
// Weights are wave-uniform -> scalar loads -> v_fmac with SGPR operand.
// Features staged in XOR-swizzled LDS tile (conflict-free reads per j).
// ---------------------------------------------------------------------------
__global__ __launch_bounds__(256) void precompute_kernel(
    const float* __restrict__ features,
    const float* __restrict__ w1,
    const float* __restrict__ w3,
    const float* __restrict__ bn2_gamma,
    const float* __restrict__ bn2_beta,
    const float* __restrict__ bn2_mean,
    const float* __restrict__ bn2_var,
    float* __restrict__ g_ws,
    float* __restrict__ y_ws)
{
    __shared__ float fbuf[4][64][64];   // 64 KiB, one 16 KiB tile per wave
    const int w = threadIdx.x >> 6;
    const int l = threadIdx.x & 63;
    const int wid  = blockIdx.x * 4 + w;   // 0..1023
    const int row0 = wid * 64;
    float (* const fb)[64] = fbuf[w];

    // ---- stage features rows [row0, row0+64), swizzled: fb[r][c^(r&31)] ----
    for (int rr = 0; rr < 64; ++rr)
        fb[rr][l ^ (rr & 31)] = features[(row0 + rr) * 64 + l];

    float acc[64];

    // ---- pass 1: g = f @ w1[2:66] ----
    #pragma unroll
    for (int cc = 0; cc < 64; ++cc) acc[cc] = 0.0f;
    #pragma unroll 4
    for (int j = 0; j < 64; ++j) {
        const float fj = fb[l][j ^ (l & 31)];         // conflict-free
        const float* __restrict__ wrow = w1 + (2 + j) * 64;  // uniform -> s_load
        #pragma unroll
        for (int cc = 0; cc < 64; ++cc) acc[cc] = fmaf(fj, wrow[cc], acc[cc]);
    }
    // transpose through LDS (same swizzle) and store coalesced
    #pragma unroll 4
    for (int cc = 0; cc < 64; ++cc) fb[l][cc ^ (l & 31)] = acc[cc];
    for (int rr = 0; rr < 64; ++rr)
        g_ws[(row0 + rr) * 64 + l] = fb[rr][l ^ (rr & 31)];

    // ---- restage features (fb was clobbered) ----
    for (int rr = 0; rr < 64; ++rr)
        fb[rr][l ^ (rr & 31)] = features[(row0 + rr) * 64 + l];

    // ---- pass 2: y = relu(bn2(f @ w3)) ----
    #pragma unroll
    for (int cc = 0; cc < 64; ++cc) acc[cc] = 0.0f;
    #pragma unroll 4
    for (int j = 0; j < 64; ++j) {
        const float fj = fb[l][j ^ (l & 31)];
        const float* __restrict__ wrow = w3 + j * 64;
        #pragma unroll
        for (int cc = 0; cc < 64; ++cc) acc[cc] = fmaf(fj, wrow[cc], acc[cc]);
    }
    #pragma unroll 4
    for (int cc = 0; cc < 64; ++cc) {
        const float s2 = bn2_gamma[cc] * rsqrtf(bn2_var[cc] + EPSV);
        const float bb = bn2_beta[cc] - bn2_mean[cc] * s2;
        fb[l][cc ^ (l & 31)] = fmaxf(fmaf(acc[cc], s2, bb), 0.0f);
    }
    for (int rr = 0; rr < 64; ++rr)
        y_ws[(row0 + rr) * 64 + l] = fb[rr][l ^ (rr & 31)];
}

// ---------------------------------------------------------------------------
// Kernel B: one wave per strided point. lane = output channel c.
// ---------------------------------------------------------------------------
__global__ __launch_bounds__(256) void gather_kernel(
    const float* __restrict__ points,
    const float* __restrict__ w1,
    const float* __restrict__ bn1_gamma,
    const float* __restrict__ bn1_beta,
    const float* __restrict__ bn1_mean,
    const float* __restrict__ bn1_var,
    const float* __restrict__ w2,
    const float* __restrict__ b2,
    const float* __restrict__ g_ws,
    const float* __restrict__ y_ws,
    float* __restrict__ d_out)
{
    const int w  = threadIdx.x >> 6;
    const int c  = threadIdx.x & 63;
    const int wid = blockIdx.x * 4 + w;      // 0..16383 : (b, strided point)
    const int b   = wid >> 12;               // / 4096
    const int pl  = wid & (MPTS - 1);
    const int n   = pl * 4;
    const int base = b * NPTS;

    const float cx = points[(base + n) * 2 + 0];
    const float cy = points[(base + n) * 2 + 1];

    // per-channel constants (hoisted out of the k loop)
    const float w10 = w1[c];
    const float w11 = w1[64 + c];
    const float w2c = w2[c];
    const float s1  = bn1_gamma[c] * rsqrtf(bn1_var[c] + EPSV);
    const float bb1 = bn1_beta[c] - bn1_mean[c] * s1;
    const float b2s = b2[0];

    float wk[16], yv[16];
    #pragma unroll
    for (int k = 0; k < 16; ++k) {
        const int off  = (k < 8) ? (k - 8) : (k - 7);   // [-8..-1, 1..8]
        const int r    = (n + off + NPTS) & NMASK;
        const int flat = base + r;
        const float tx = points[flat * 2 + 0] - cx;
        const float ty = points[flat * 2 + 1] - cy;
        const float g  = g_ws[flat * 64 + c];
        const float h  = fmaxf(fmaf(g + tx * w10 + ty * w11, s1, bb1), 0.0f);
        float v = h * w2c;
        #pragma unroll
        for (int m = 1; m < 64; m <<= 1) v += __shfl_xor(v, m);
        wk[k] = v + b2s;                 // replicated across lanes
        yv[k] = y_ws[flat * 64 + c];
    }

    // in-lane softmax over the 16 neighbor scores, then weighted sum of y
    float mx = wk[0];
    #pragma unroll
    for (int k = 1; k < 16; ++k) mx = fmaxf(mx, wk[k]);
    float se = 0.0f, o = 0.0f;
    #pragma unroll
    for (int k = 0; k < 16; ++k) {
        const float e = __expf(wk[k] - mx);
        se += e;
        o  = fmaf(e, yv[k], o);
    }
    o /= se;

    float* __restrict__ outp = d_out + (4 * MPTS * 2);   // after points_out
    outp[(b * MPTS + pl) * 64 + c] = o;
    if (c < 2)
        d_out[(b * MPTS + pl) * 2 + c] = points[(base + n) * 2 + c];
}

// ---------------------------------------------------------------------------
extern "C" void kernel_launch(void* const* d_in, const int* in_sizes, int n_in,
                              void* d_out, int out_size, void* d_ws, size_t ws_size,
                              hipStream_t stream)
{
    const float* points    = (const float*)d_in[0];
    const float* features  = (const float*)d_in[1];
    const float* w1        = (const float*)d_in[2];
    const float* bn1_gamma = (const float*)d_in[3];
    const float* bn1_beta  = (const float*)d_in[4];
    const float* bn1_mean  = (const float*)d_in[5];
    const float* bn1_var   = (const float*)d_in[6];
    const float* w2        = (const float*)d_in[7];
    const float* b2        = (const float*)d_in[8];
    const float* w3        = (const float*)d_in[9];
    const float* bn2_gamma = (const float*)d_in[10];
    const float* bn2_beta  = (const float*)d_in[11];
    const float* bn2_mean  = (const float*)d_in[12];
    const float* bn2_var   = (const float*)d_in[13];

    float* g_ws = (float*)d_ws;                    // NROWS*64 f32 = 16.7 MB
    float* y_ws = g_ws + (size_t)NROWS * 64;       // NROWS*64 f32 = 16.7 MB

    precompute_kernel<<<256, 256, 0, stream>>>(
        features, w1, w3, bn2_gamma, bn2_beta, bn2_mean, bn2_var, g_ws, y_ws);

    gather_kernel<<<4096, 256, 0, stream>>>(
        points, w1, bn1_gamma, bn1_beta, bn1_mean, bn1_var, w2, b2,
        g_ws, y_ws, (float*)d_out);
}

// Round 2
// 40.114 us; speedup vs baseline: 3.4562x; 3.4562x over previous
//
#include <hip/hip_runtime.h>
#include <hip/hip_bf16.h>

// SymmetricTransitionDown: B=4, N=16384, C=64, O=64, RADIUS=8, STRIDE=4, S=16.
#define NPTS   16384
#define NMASK  16383
#define MPTS   4096
#define NROWS  65536
#define EPSV   1e-5f

typedef __attribute__((ext_vector_type(8))) short short8_t;   // 8 bf16 = 4 VGPR
typedef __attribute__((ext_vector_type(4))) short short4_t;   // 8-byte store
typedef __attribute__((ext_vector_type(4))) float f32x4;

static __device__ __forceinline__ short f2bf(float x) {
    union { __hip_bfloat16 b; short s; } u; u.b = __float2bfloat16(x); return u.s;
}

// ---------------------------------------------------------------------------
// Kernel A (MFMA): for all 65536 rows r:
//   g[r][c] = sum_j f[r][j] * w1[2+j][c]          (bf16 out)
//   y[r][c] = relu(bn2(sum_j f[r][j] * w3[j][c])) (bf16 out)
// One 16-row tile per wave; 4096 waves. Weights staged once per block into a
// swizzled LDS tile (stored W^T col-major: [mat][col][k], byte ^= (col&7)<<4
// on the k-chunk -> conflict-(near-)free ds_read_b128 fragments).
// Operand swap: D = mfma(Wfrag as A, Ffrag as B) so D.col = feature row,
// D.row = channel -> each lane stores 4 consecutive bf16 channels (8 B).
// ---------------------------------------------------------------------------
__global__ __launch_bounds__(256) void precompute_mfma(
    const float* __restrict__ features,
    const float* __restrict__ w1,
    const float* __restrict__ w3,
    const float* __restrict__ bn2_gamma,
    const float* __restrict__ bn2_beta,
    const float* __restrict__ bn2_mean,
    const float* __restrict__ bn2_var,
    short* __restrict__ g_ws,
    short* __restrict__ y_ws)
{
    __shared__ short wlds[8192];          // 16 KiB: [mat][col=64][k=64] bf16, swizzled
    __shared__ float s2l[64], bb2l[64];
    const int tid = threadIdx.x;

    // ---- stage weights (bf16, transposed, swizzled) ----
    for (int e = tid; e < 8192; e += 256) {
        const int mat = e >> 12, idx = e & 4095;
        const int k = idx >> 6, col = idx & 63;
        const float v = mat ? w3[idx] : w1[idx + 128];        // w1 rows 2..65
        const int byte = mat * 8192 + col * 128 + ((k * 2) ^ ((col & 7) << 4));
        *(short*)((char*)wlds + byte) = f2bf(v);
    }
    if (tid < 64) {
        const float s = bn2_gamma[tid] * rsqrtf(bn2_var[tid] + EPSV);
        s2l[tid] = s;
        bb2l[tid] = bn2_beta[tid] - bn2_mean[tid] * s;
    }
    __syncthreads();

    const int l    = tid & 63;
    const int wid  = blockIdx.x * 4 + (tid >> 6);   // 0..4095
    const int row0 = wid * 16;
    const int r    = l & 15;                        // feature row within tile
    const int kg   = l >> 4;                        // k-group 0..3

    // ---- F fragments (B operand): lane holds f[row0+r][s*32 + kg*8 + e] ----
    short8_t ff[2];
    #pragma unroll
    for (int s = 0; s < 2; ++s) {
        const float4* fp =
            (const float4*)(features + (size_t)(row0 + r) * 64 + s * 32 + kg * 8);
        const float4 a = fp[0], b = fp[1];
        short8_t f;
        f[0] = f2bf(a.x); f[1] = f2bf(a.y); f[2] = f2bf(a.z); f[3] = f2bf(a.w);
        f[4] = f2bf(b.x); f[5] = f2bf(b.y); f[6] = f2bf(b.z); f[7] = f2bf(b.w);
        ff[s] = f;
    }

    const f32x4 z = {0.0f, 0.0f, 0.0f, 0.0f};
    f32x4 acc[2][4] = {{z, z, z, z}, {z, z, z, z}};

    // ---- 16 MFMAs: acc[mat][t] over 4 col-tiles x 2 K-steps x 2 matrices ----
    #pragma unroll
    for (int mat = 0; mat < 2; ++mat)
        #pragma unroll
        for (int t = 0; t < 4; ++t)
            #pragma unroll
            for (int s = 0; s < 2; ++s) {
                const int col  = 16 * t + r;
                const int byte = mat * 8192 + col * 128 +
                                 ((s * 64 + kg * 16) ^ ((r & 7) << 4));
                const short8_t wf = *(const short8_t*)((const char*)wlds + byte);
                acc[mat][t] =
                    __builtin_amdgcn_mfma_f32_16x16x32_bf16(wf, ff[s], acc[mat][t], 0, 0, 0);
            }

    // ---- epilogue: lane owns channels 16t + kg*4 + j of row row0+r ----
    const int c0 = kg * 4;
    #pragma unroll
    for (int t = 0; t < 4; ++t) {
        short4_t gv;
        #pragma unroll
        for (int j = 0; j < 4; ++j) gv[j] = f2bf(acc[0][t][j]);
        *(short4_t*)(g_ws + (size_t)(row0 + r) * 64 + 16 * t + c0) = gv;

        short4_t yv;
        #pragma unroll
        for (int j = 0; j < 4; ++j) {
            const int c = 16 * t + c0 + j;
            yv[j] = f2bf(fmaxf(fmaf(acc[1][t][j], s2l[c], bb2l[c]), 0.0f));
        }
        *(short4_t*)(y_ws + (size_t)(row0 + r) * 64 + 16 * t + c0) = yv;
    }
}

// ---------------------------------------------------------------------------
// Kernel B: one wave per strided point. lane = output channel c.
// ---------------------------------------------------------------------------
__global__ __launch_bounds__(256) void gather_kernel(
    const float* __restrict__ points,
    const float* __restrict__ w1,
    const float* __restrict__ bn1_gamma,
    const float* __restrict__ bn1_beta,
    const float* __restrict__ bn1_mean,
    const float* __restrict__ bn1_var,
    const float* __restrict__ w2,
    const float* __restrict__ b2,
    const __hip_bfloat16* __restrict__ g_ws,
    const __hip_bfloat16* __restrict__ y_ws,
    float* __restrict__ d_out)
{
    const int w   = threadIdx.x >> 6;
    const int c   = threadIdx.x & 63;
    const int wid = blockIdx.x * 4 + w;      // 0..16383 : (b, strided point)
    const int b   = wid >> 12;               // / 4096
    const int pl  = wid & (MPTS - 1);
    const int n   = pl * 4;
    const int base = b * NPTS;

    const float cx = points[(base + n) * 2 + 0];
    const float cy = points[(base + n) * 2 + 1];

    const float w10 = w1[c];
    const float w11 = w1[64 + c];
    const float w2c = w2[c];
    const float s1  = bn1_gamma[c] * rsqrtf(bn1_var[c] + EPSV);
    const float bb1 = bn1_beta[c] - bn1_mean[c] * s1;
    const float b2s = b2[0];

    float wk[16], yv[16];
    #pragma unroll
    for (int k = 0; k < 16; ++k) {
        const int off  = (k < 8) ? (k - 8) : (k - 7);   // [-8..-1, 1..8]
        const int r    = (n + off + NPTS) & NMASK;
        const int flat = base + r;
        const float tx = points[flat * 2 + 0] - cx;
        const float ty = points[flat * 2 + 1] - cy;
        const float g  = __bfloat162float(g_ws[(size_t)flat * 64 + c]);
        const float h  = fmaxf(fmaf(g + tx * w10 + ty * w11, s1, bb1), 0.0f);
        float v = h * w2c;
        #pragma unroll
        for (int m = 1; m < 64; m <<= 1) v += __shfl_xor(v, m);
        wk[k] = v + b2s;
        yv[k] = __bfloat162float(y_ws[(size_t)flat * 64 + c]);
    }

    float mx = wk[0];
    #pragma unroll
    for (int k = 1; k < 16; ++k) mx = fmaxf(mx, wk[k]);
    float se = 0.0f, o = 0.0f;
    #pragma unroll
    for (int k = 0; k < 16; ++k) {
        const float e = __expf(wk[k] - mx);
        se += e;
        o  = fmaf(e, yv[k], o);
    }
    o /= se;

    float* __restrict__ outp = d_out + (4 * MPTS * 2);
    outp[(b * MPTS + pl) * 64 + c] = o;
    if (c < 2)
        d_out[(b * MPTS + pl) * 2 + c] = points[(base + n) * 2 + c];
}

// ---------------------------------------------------------------------------
extern "C" void kernel_launch(void* const* d_in, const int* in_sizes, int n_in,
                              void* d_out, int out_size, void* d_ws, size_t ws_size,
                              hipStream_t stream)
{
    const float* points    = (const float*)d_in[0];
    const float* features  = (const float*)d_in[1];
    const float* w1        = (const float*)d_in[2];
    const float* bn1_gamma = (const float*)d_in[3];
    const float* bn1_beta  = (const float*)d_in[4];
    const float* bn1_mean  = (const float*)d_in[5];
    const float* bn1_var   = (const float*)d_in[6];
    const float* w2        = (const float*)d_in[7];
    const float* b2        = (const float*)d_in[8];
    const float* w3        = (const float*)d_in[9];
    const float* bn2_gamma = (const float*)d_in[10];
    const float* bn2_beta  = (const float*)d_in[11];
    const float* bn2_mean  = (const float*)d_in[12];
    const float* bn2_var   = (const float*)d_in[13];

    short* g_ws = (short*)d_ws;                    // NROWS*64 bf16 = 8.4 MB
    short* y_ws = g_ws + (size_t)NROWS * 64;       // NROWS*64 bf16 = 8.4 MB

    precompute_mfma<<<1024, 256, 0, stream>>>(
        features, w1, w3, bn2_gamma, bn2_beta, bn2_mean, bn2_var, g_ws, y_ws);

    gather_kernel<<<4096, 256, 0, stream>>>(
        points, w1, bn1_gamma, bn1_beta, bn1_mean, bn1_var, w2, b2,
        (const __hip_bfloat16*)g_ws, (const __hip_bfloat16*)y_ws, (float*)d_out);
}

// Round 3
// 22.641 us; speedup vs baseline: 6.1236x; 1.7718x over previous
//
#include <hip/hip_runtime.h>
#include <hip/hip_bf16.h>

// SymmetricTransitionDown fused: B=4, N=16384, C=64, O=64, R=8, STRIDE=4, S=16.
// One block = 128 output rows (+16 halo rows each side = 160 LDS rows),
// 32 strided points, 256 threads (4 waves). 512 blocks total.
#define NPTS   16384
#define NMASK  16383
#define EPSV   1e-5f
#define OUTOFF 32768            // points_out = 4*4096*2 floats, outputs follow

typedef __attribute__((ext_vector_type(8))) short short8_t;
typedef __attribute__((ext_vector_type(4))) short short4_t;
typedef __attribute__((ext_vector_type(4))) float f32x4;

static __device__ __forceinline__ short f2bf(float x) {
    union { __hip_bfloat16 b; short s; } u; u.b = __float2bfloat16(x); return u.s;
}
static __device__ __forceinline__ float bf2f(short s) {
    union { float f; unsigned u; } v; v.u = ((unsigned)(unsigned short)s) << 16; return v.f;
}

__global__ __launch_bounds__(256, 2) void fused_std_kernel(
    const float* __restrict__ points,
    const float* __restrict__ features,
    const float* __restrict__ w1,
    const float* __restrict__ bn1_gamma, const float* __restrict__ bn1_beta,
    const float* __restrict__ bn1_mean,  const float* __restrict__ bn1_var,
    const float* __restrict__ w2,
    const float* __restrict__ w3,
    const float* __restrict__ bn2_gamma, const float* __restrict__ bn2_beta,
    const float* __restrict__ bn2_mean,  const float* __restrict__ bn2_var,
    float* __restrict__ d_out)
{
    // LDS: 16384 + 20480 + 20480 + 1280 + 1792 + 256 = 60672 B -> 2 blocks/CU
    __shared__ __align__(16) short wlds[8192];      // W^T bf16 [mat][col][k], swizzled
    __shared__ __align__(16) short gpls[160 * 64];  // G' bf16 [row][c], slot^=(row&7)
    __shared__ __align__(16) short ylds[160 * 64];  // y  bf16 [row][c], slot^=(row&7)
    __shared__ __align__(16) float ptsl[160 * 2];
    __shared__ float cP[64], cQ[64], cW2[64], cS1[64], cB1[64], cS2[64], cB2[64];
    __shared__ __align__(16) float swp[4][16];      // per-wave score scratch

    const int tid = threadIdx.x;
    const int wv  = tid >> 6, l = tid & 63;
    const int r   = l & 15,  kg = l >> 4;
    const int bi  = blockIdx.x >> 7;                // batch
    const int n0  = (blockIdx.x & 127) * 128;       // first output row in batch
    const int base = bi * NPTS;

    // ---- issue feature loads for this wave's tiles FIRST (hide latency) ----
    struct TF { float4 a, b, c, d; };
    auto loadTile = [&](int ti) {
        const int gr = base + ((n0 - 16 + ti * 16 + r) & NMASK);
        const float* fp = features + (size_t)gr * 64 + kg * 8;
        TF t;
        t.a = *(const float4*)(fp);
        t.b = *(const float4*)(fp + 4);
        t.c = *(const float4*)(fp + 32);
        t.d = *(const float4*)(fp + 36);
        return t;
    };
    TF T0 = loadTile(wv);
    TF T1 = loadTile(wv + 4);
    TF T2;
    if (wv < 2) T2 = loadTile(wv + 8);

    // ---- stage weights (bf16, transposed, swizzled), constants, points ----
    for (int e = tid; e < 8192; e += 256) {
        const int mat = e >> 12, idx = e & 4095;
        const int k = idx >> 6, col = idx & 63;
        const float v = mat ? w3[idx] : w1[idx + 128];    // w1 rows 2..65
        const int byte = mat * 8192 + col * 128 + ((k * 2) ^ ((col & 7) << 4));
        *(short*)((char*)wlds + byte) = f2bf(v);
    }
    if (tid < 64) {
        const float s1 = bn1_gamma[tid] * rsqrtf(bn1_var[tid] + EPSV);
        cS1[tid] = s1;
        cB1[tid] = bn1_beta[tid] - bn1_mean[tid] * s1;
        cP[tid]  = s1 * w1[tid];          // s1 * w1[0][c]
        cQ[tid]  = s1 * w1[64 + tid];     // s1 * w1[1][c]
        cW2[tid] = w2[tid];
        const float s2 = bn2_gamma[tid] * rsqrtf(bn2_var[tid] + EPSV);
        cS2[tid] = s2;
        cB2[tid] = bn2_beta[tid] - bn2_mean[tid] * s2;
    }
    for (int t = tid; t < 160; t += 256) {
        const int gr = base + ((n0 - 16 + t) & NMASK);
        *(float2*)&ptsl[t * 2] = *(const float2*)&points[(size_t)gr * 2];
    }
    __syncthreads();

    // ---- phase 1: per 16-row tile, 16 MFMAs -> G'(bf16) & y(bf16) in LDS ----
    auto processTile = [&](const TF& t, int ti) {
        short8_t f0, f1;
        f0[0]=f2bf(t.a.x); f0[1]=f2bf(t.a.y); f0[2]=f2bf(t.a.z); f0[3]=f2bf(t.a.w);
        f0[4]=f2bf(t.b.x); f0[5]=f2bf(t.b.y); f0[6]=f2bf(t.b.z); f0[7]=f2bf(t.b.w);
        f1[0]=f2bf(t.c.x); f1[1]=f2bf(t.c.y); f1[2]=f2bf(t.c.z); f1[3]=f2bf(t.c.w);
        f1[4]=f2bf(t.d.x); f1[5]=f2bf(t.d.y); f1[6]=f2bf(t.d.z); f1[7]=f2bf(t.d.w);
        const f32x4 z = {0.f, 0.f, 0.f, 0.f};
        f32x4 acc0[4] = {z, z, z, z}, acc1[4] = {z, z, z, z};
        #pragma unroll
        for (int tt = 0; tt < 4; ++tt) {
            const int col = 16 * tt + r;
            #pragma unroll
            for (int s = 0; s < 2; ++s) {
                const int wb = col * 128 + ((s * 64 + kg * 16) ^ ((r & 7) << 4));
                const short8_t wa = *(const short8_t*)((const char*)wlds + wb);
                acc0[tt] = __builtin_amdgcn_mfma_f32_16x16x32_bf16(wa, s ? f1 : f0, acc0[tt], 0, 0, 0);
                const short8_t wb3 = *(const short8_t*)((const char*)wlds + 8192 + wb);
                acc1[tt] = __builtin_amdgcn_mfma_f32_16x16x32_bf16(wb3, s ? f1 : f0, acc1[tt], 0, 0, 0);
            }
        }
        const int row = ti * 16 + r;      // D: col=l&15 -> row, row=(l>>4)*4+j -> channel
        #pragma unroll
        for (int tt = 0; tt < 4; ++tt) {
            const int c0 = 16 * tt + kg * 4;
            short4_t gq, yq;
            #pragma unroll
            for (int j = 0; j < 4; ++j) {
                gq[j] = f2bf(fmaf(acc0[tt][j], cS1[c0 + j], cB1[c0 + j]));
                yq[j] = f2bf(fmaxf(fmaf(acc1[tt][j], cS2[c0 + j], cB2[c0 + j]), 0.0f));
            }
            const int byte = row * 128 +
                (((2 * tt + (kg >> 1)) ^ (row & 7)) << 4) + ((kg & 1) << 3);
            *(short4_t*)((char*)gpls + byte) = gq;
            *(short4_t*)((char*)ylds + byte) = yq;
        }
    };
    processTile(T0, wv);
    processTile(T1, wv + 4);
    if (wv < 2) processTile(T2, wv + 8);
    __syncthreads();

    // ---- phase 2: one wave per point, scores via MFMA (A=relu'd 16x64, B=w2 col0) ----
    const int knb  = r;                                  // neighbor index 0..15
    const int cgrp = kg;                                 // c-chunk 0..3
    const int offk = (knb < 8) ? knb - 8 : knb - 7;      // [-8..-1, 1..8]
    float P0[8], P1[8], Q0[8], Q1[8];
    #pragma unroll
    for (int e = 0; e < 8; ++e) {
        P0[e] = cP[cgrp * 8 + e];  P1[e] = cP[32 + cgrp * 8 + e];
        Q0[e] = cQ[cgrp * 8 + e];  Q1[e] = cQ[32 + cgrp * 8 + e];
    }
    short8_t Bw0, Bw1;                                   // B[k][col]: col0 = w2
    #pragma unroll
    for (int e = 0; e < 8; ++e) {
        Bw0[e] = f2bf(knb == 0 ? cW2[cgrp * 8 + e] : 0.0f);
        Bw1[e] = f2bf(knb == 0 ? cW2[32 + cgrp * 8 + e] : 0.0f);
    }

    for (int p = wv; p < 32; p += 4) {
        const int crow = 16 + 4 * p;
        const int nrow = crow + offk;
        const float tx = ptsl[nrow * 2]     - ptsl[crow * 2];
        const float ty = ptsl[nrow * 2 + 1] - ptsl[crow * 2 + 1];
        const short8_t g0 = *(const short8_t*)((const char*)gpls +
            nrow * 128 + ((cgrp ^ (nrow & 7)) << 4));
        const short8_t g1 = *(const short8_t*)((const char*)gpls +
            nrow * 128 + (((4 + cgrp) ^ (nrow & 7)) << 4));
        short8_t A0, A1;                                  // A[row=knb][k=c]
        #pragma unroll
        for (int e = 0; e < 8; ++e) {
            const float a0 = bf2f(g0[e]) + tx * P0[e] + ty * Q0[e];
            A0[e] = f2bf(fmaxf(a0, 0.0f));
            const float a1 = bf2f(g1[e]) + tx * P1[e] + ty * Q1[e];
            A1[e] = f2bf(fmaxf(a1, 0.0f));
        }
        f32x4 D = {0.f, 0.f, 0.f, 0.f};
        D = __builtin_amdgcn_mfma_f32_16x16x32_bf16(A0, Bw0, D, 0, 0, 0);
        D = __builtin_amdgcn_mfma_f32_16x16x32_bf16(A1, Bw1, D, 0, 0, 0);
        // D col0 lives in lanes l&15==0; row (neighbor) = (l>>4)*4 + j
        if (knb == 0) *(f32x4*)&swp[wv][cgrp * 4] = D;
        asm volatile("s_waitcnt lgkmcnt(0)" ::: "memory");
        float sc[16];
        #pragma unroll
        for (int q = 0; q < 4; ++q) {
            const f32x4 sv = *(const f32x4*)&swp[wv][q * 4];
            sc[q*4+0] = sv[0]; sc[q*4+1] = sv[1]; sc[q*4+2] = sv[2]; sc[q*4+3] = sv[3];
        }
        float mx = sc[0];
        #pragma unroll
        for (int k = 1; k < 16; ++k) mx = fmaxf(mx, sc[k]);
        float se = 0.0f, o = 0.0f;
        #pragma unroll
        for (int k = 0; k < 16; ++k) {
            const float ek = __expf(sc[k] - mx);
            se += ek;
            const int rk = crow + ((k < 8) ? k - 8 : k - 7);
            const short yb = *(const short*)((const char*)ylds +
                rk * 128 + ((((l >> 3) ^ (rk & 7))) << 4) + ((l & 7) << 1));
            o = fmaf(ek, bf2f(yb), o);
        }
        o /= se;
        const int pl = (n0 >> 2) + p;
        d_out[OUTOFF + ((size_t)bi * 4096 + pl) * 64 + l] = o;
        if (l < 2)
            d_out[((size_t)bi * 4096 + pl) * 2 + l] = ptsl[crow * 2 + l];
    }
}

// ---------------------------------------------------------------------------
extern "C" void kernel_launch(void* const* d_in, const int* in_sizes, int n_in,
                              void* d_out, int out_size, void* d_ws, size_t ws_size,
                              hipStream_t stream)
{
    const float* points    = (const float*)d_in[0];
    const float* features  = (const float*)d_in[1];
    const float* w1        = (const float*)d_in[2];
    const float* bn1_gamma = (const float*)d_in[3];
    const float* bn1_beta  = (const float*)d_in[4];
    const float* bn1_mean  = (const float*)d_in[5];
    const float* bn1_var   = (const float*)d_in[6];
    const float* w2        = (const float*)d_in[7];
    // d_in[8] = b2: shift-invariant under softmax, intentionally unused
    const float* w3        = (const float*)d_in[9];
    const float* bn2_gamma = (const float*)d_in[10];
    const float* bn2_beta  = (const float*)d_in[11];
    const float* bn2_mean  = (const float*)d_in[12];
    const float* bn2_var   = (const float*)d_in[13];

    fused_std_kernel<<<512, 256, 0, stream>>>(
        points, features, w1, bn1_gamma, bn1_beta, bn1_mean, bn1_var,
        w2, w3, bn2_gamma, bn2_beta, bn2_mean, bn2_var, (float*)d_out);
}